// Round 20
// baseline (533.633 us; speedup 1.0000x reference)
//
#include <hip/hip_runtime.h>

namespace {

constexpr int Bb = 8;
constexpr int Nn = 4097;
constexpr int Cc = 768;
constexpr int Hh = 12;
constexpr int HD = 64;
constexpr int Aa = 49;
constexpr int LDQ = 3 * Cc;        // 2304 (qkv row stride, in shorts)
constexpr int NCH = 16;            // j-chunks for agent attention
constexpr int CHUNK = 256;         // 64-aligned; last chunk absorbs row 4096
constexpr float SCALE = 0.125f;    // hd^-0.5
constexpr int KP = 1536;           // WEIGHT packed row length (hi 768|lo 768)
constexpr int KA = 768;            // ACTIVATION packed row length (RNE bf16)
constexpr int TPQ = 4;             // q-tiles per q_attn_dwc block

typedef short s16x8 __attribute__((ext_vector_type(8)));
typedef short s16x4 __attribute__((ext_vector_type(4)));
typedef float f32x4 __attribute__((ext_vector_type(4)));

struct HL { short h, l; };

// Split fp32 into hi (truncated bf16, exact bits) + lo (RNE bf16 of residual).
__device__ inline HL splitbf(float v) {
  unsigned u = __float_as_uint(v);
  HL r;
  r.h = (short)(u >> 16);
  float hf = __uint_as_float(u & 0xffff0000u);
  float lf = v - hf;
  unsigned ul = __float_as_uint(lf);
  r.l = (short)((ul + 0x7fffu + ((ul >> 16) & 1u)) >> 16);
  return r;
}

__device__ inline short bf16rne(float v) {
  unsigned u = __float_as_uint(v);
  return (short)((u + 0x7fffu + ((u >> 16) & 1u)) >> 16);
}
__device__ inline float bf2f(short s) {
  return __uint_as_float((unsigned)(unsigned short)s << 16);
}

// async global->LDS, 16B per lane (linear dest)
__device__ inline void gload16(const short* g, void* l) {
  __builtin_amdgcn_global_load_lds(
      (const __attribute__((address_space(1))) void*)g,
      (__attribute__((address_space(3))) void*)l, 16, 0, 0);
}

// Packed layout: per row, 12 windows of 64 elems (8 chunks of 8);
// physical chunk = logical chunk ^ (row&7).
// Weights: split hi/lo (REQUIRED — RNE-only W fails threshold through K=768).
// Activations/attention operands: single RNE bf16 (softmax-attenuated error).
// qkv / at / av stored as RNE bf16 (every consumer RNE'd them anyway).

// ---------------------------------------------------------------------------
// Pack activations: src[M][768] fp32 -> dst[M][768] RNE bf16 (swizzled).
// ---------------------------------------------------------------------------
__global__ __launch_bounds__(256) void pack_act(
    const float* __restrict__ src, short* __restrict__ dst, int M) {
  int idx = blockIdx.x * 256 + threadIdx.x;
  if (idx >= M * 96) return;
  int m = idx / 96, kc = idx - m * 96;
  const float* s = src + (size_t)m * 768 + kc * 8;
  float4 v0 = *(const float4*)s;
  float4 v1 = *(const float4*)(s + 4);
  s16x8 hv;
  hv[0] = bf16rne(v0.x); hv[1] = bf16rne(v0.y);
  hv[2] = bf16rne(v0.z); hv[3] = bf16rne(v0.w);
  hv[4] = bf16rne(v1.x); hv[5] = bf16rne(v1.y);
  hv[6] = bf16rne(v1.z); hv[7] = bf16rne(v1.w);
  int win = (kc >> 3) * 64;
  int jj = ((kc & 7) ^ (m & 7)) * 8;
  *(s16x8*)&dst[(size_t)m * KA + win + jj] = hv;
}

// ---------------------------------------------------------------------------
// Pack weights: W[768][N] fp32 -> Wpk[N][1536] bf16 split, key (n&7).
// ---------------------------------------------------------------------------
__global__ __launch_bounds__(256) void pack_w(
    const float* __restrict__ W, short* __restrict__ Wpk, int N) {
  int idx = blockIdx.x * 256 + threadIdx.x;
  if (idx >= 96 * N) return;
  int kc = idx / N, n = idx - kc * N;
  s16x8 hv, lv;
#pragma unroll
  for (int i = 0; i < 8; ++i) {
    HL r = splitbf(W[(size_t)(kc * 8 + i) * N + n]);
    hv[i] = r.h; lv[i] = r.l;
  }
  int win = (kc >> 3) * 64;
  int jj = ((kc & 7) ^ (n & 7)) * 8;
  short* d = Wpk + (size_t)n * KP;
  *(s16x8*)&d[win + jj] = hv;
  *(s16x8*)&d[768 + win + jj] = lv;
}

// ---------------------------------------------------------------------------
// C[M x N] = A @ B (+bias): A = RNE bf16 [M][768], B = split [N][1536].
// 2 products -> 64 MFMA per kt, 3 staged planes (48KB LDS). R12 barrier
// structure (frozen). BF16OUT: direct RNE bf16 stores (R18 — the LDS
// re-gather epilogue measured neutral-negative in R19, reverted).
// ---------------------------------------------------------------------------
template <bool BF16OUT>
__global__ __launch_bounds__(256) void gemm_pk2(
    const short* __restrict__ Apk, const short* __restrict__ Bpk,
    void* __restrict__ Cm, const float* __restrict__ bias,
    int Mr, int ldc, int nch, int nwg) {
  __shared__ __align__(16) short AsH[128 * 64];
  __shared__ __align__(16) short BsH[128 * 64], BsL[128 * 64];
  const int t = threadIdx.x;
  const int lane = t & 63;
  const int w = t >> 6;
  const int wr = w >> 1, wc = w & 1;
  const int l15 = lane & 15, l4 = lane >> 4;

  const int j = blockIdx.x;
  const int q = nwg >> 3, r = nwg & 7;
  const int xcd = j & 7, pos = j >> 3;
  const int logical =
      (xcd < r ? xcd * (q + 1) : r * (q + 1) + (xcd - r) * q) + pos;
  const int mt = logical / nch, nc = logical - mt * nch;
  const int m0 = mt * 128, n0 = nc * 128;

  f32x4 acc[4][4];
#pragma unroll
  for (int mi = 0; mi < 4; ++mi)
#pragma unroll
    for (int ni = 0; ni < 4; ++ni) acc[mi][ni] = (f32x4){0.f, 0.f, 0.f, 0.f};

  for (int kt = 0; kt < 12; ++kt) {
    const short* Ab = Apk + (size_t)m0 * KA + kt * 64;
    const short* Bt = Bpk + (size_t)n0 * KP + kt * 64;
    __syncthreads();
#pragma unroll
    for (int i = 0; i < 4; ++i) {
      const int o = (i * 256 + t) * 16;   // byte offset in 16KB plane
      const int row = o >> 7;
      const int ce = (o & 127) >> 1;      // element col (physical)
      gload16(Ab + (size_t)row * KA + ce, (char*)AsH + o);
      gload16(Bt + (size_t)row * KP + ce, (char*)BsH + o);
      gload16(Bt + (size_t)row * KP + 768 + ce, (char*)BsL + o);
    }
    __syncthreads();
#pragma unroll
    for (int ks = 0; ks < 2; ++ks) {
      s16x8 ah[4], bh[4], bl[4];
#pragma unroll
      for (int mi = 0; mi < 4; ++mi) {
        int rr = wr * 64 + mi * 16 + l15;
        ah[mi] = *(const s16x8*)&AsH[rr * 64 + ((((ks << 2) + l4) ^ (l15 & 7)) << 3)];
      }
#pragma unroll
      for (int ni = 0; ni < 4; ++ni) {
        int rr = wc * 64 + ni * 16 + l15;
        int off = rr * 64 + ((((ks << 2) + l4) ^ (l15 & 7)) << 3);
        bh[ni] = *(const s16x8*)&BsH[off];
        bl[ni] = *(const s16x8*)&BsL[off];
      }
#pragma unroll
      for (int mi = 0; mi < 4; ++mi)
#pragma unroll
        for (int ni = 0; ni < 4; ++ni) {
          acc[mi][ni] = __builtin_amdgcn_mfma_f32_16x16x32_bf16(
              ah[mi], bh[ni], acc[mi][ni], 0, 0, 0);
          acc[mi][ni] = __builtin_amdgcn_mfma_f32_16x16x32_bf16(
              ah[mi], bl[ni], acc[mi][ni], 0, 0, 0);
        }
    }
  }

#pragma unroll
  for (int mi = 0; mi < 4; ++mi) {
#pragma unroll
    for (int jr = 0; jr < 4; ++jr) {
      int gr = m0 + wr * 64 + mi * 16 + l4 * 4 + jr;
      if (gr < Mr) {
#pragma unroll
        for (int ni = 0; ni < 4; ++ni) {
          int gc = n0 + wc * 64 + ni * 16 + l15;
          float v = acc[mi][ni][jr];
          if (bias) v += bias[gc];
          if constexpr (BF16OUT) {
            ((short*)Cm)[(size_t)gr * ldc + gc] = bf16rne(v);
          } else {
            ((float*)Cm)[(size_t)gr * ldc + gc] = v;
          }
        }
      }
    }
  }
}

// ---------------------------------------------------------------------------
// Adaptive-pool agents: atb[bg,a,c] = RNE(mean over q rows of bf16 q).
// ---------------------------------------------------------------------------
__global__ __launch_bounds__(192) void pool_agents(
    const short* __restrict__ qkvb, short* __restrict__ atb) {
  const int ba = blockIdx.x;
  const int bg = ba / Aa, a = ba % Aa;
  const int s = (a * 4096) / 49;
  const int e = ((a + 1) * 4096 + 48) / 49;
  const float w = 1.0f / (float)(e - s);
  const int c4 = threadIdx.x * 4;
  f32x4 sum = (f32x4){0.f, 0.f, 0.f, 0.f};
  for (int l = s; l < e; ++l) {
    const s16x4 v = *(const s16x4*)&qkvb[(size_t)(bg * Nn + l) * LDQ + c4];
    sum[0] += bf2f(v[0]); sum[1] += bf2f(v[1]);
    sum[2] += bf2f(v[2]); sum[3] += bf2f(v[3]);
  }
  s16x4 o;
  o[0] = bf16rne(sum[0] * w); o[1] = bf16rne(sum[1] * w);
  o[2] = bf16rne(sum[2] * w); o[3] = bf16rne(sum[3] * w);
  *(s16x4*)&atb[(size_t)(bg * Aa + a) * Cc + c4] = o;
}

// ---------------------------------------------------------------------------
// Agent attention: all operands RNE bf16, staging = direct bit-copy.
// 24KB LDS -> 6 blocks/CU. 3 barriers/tile.
// ---------------------------------------------------------------------------
__global__ __launch_bounds__(256) void agent_attn_mfma(
    const short* __restrict__ qkvb, const short* __restrict__ atb,
    float* __restrict__ paccv, float* __restrict__ paccs) {
  const int chunk = blockIdx.x, h = blockIdx.y, bg = blockIdx.z;
  __shared__ __align__(16) short AhH[4096];   // ah [a][d]
  __shared__ __align__(16) short KH[4096];    // K [j][d]; P aliases
  __shared__ __align__(16) short VtH[4096];   // V^T [c][j]
  const int t = threadIdx.x;
  const int w = t >> 6, lane = t & 63, l15 = lane & 15, l4 = lane >> 4;

  for (int idx = t; idx < 512; idx += 256) {
    int a = idx >> 3, c8 = idx & 7;
    s16x8 hv = (s16x8)(short)0;
    if (a < Aa)
      hv = *(const s16x8*)&atb[(size_t)(bg * Aa + a) * Cc + h * HD + c8 * 8];
    *(s16x8*)&AhH[a * 64 + ((c8 ^ (a & 7)) << 3)] = hv;
  }

  f32x4 acc[4];
#pragma unroll
  for (int ni = 0; ni < 4; ++ni) acc[ni] = (f32x4){0.f, 0.f, 0.f, 0.f};
  float rs[4] = {0.f, 0.f, 0.f, 0.f};

  const int jstart = chunk * CHUNK;
  const int jend = (chunk == NCH - 1) ? Nn : jstart + CHUNK;
  const int srow = t >> 2, sc0 = (t & 3) * 16;

  for (int j0 = jstart; j0 < jend; j0 += 64) {
    __syncthreads();   // prev tile's S/PV reads done
    {
      int jg = j0 + srow;
      s16x8 k0 = (s16x8)(short)0, k1 = k0, v0 = k0, v1 = k0;
      if (jg < jend) {
        const short* p = &qkvb[(size_t)(bg * Nn + jg) * LDQ + Cc + h * HD + sc0];
        k0 = *(const s16x8*)p;
        k1 = *(const s16x8*)(p + 8);
        v0 = *(const s16x8*)(p + Cc);
        v1 = *(const s16x8*)(p + Cc + 8);
      }
      int ch = sc0 >> 3;
      *(s16x8*)&KH[srow * 64 + (((ch + 0) ^ (srow & 7)) << 3)] = k0;
      *(s16x8*)&KH[srow * 64 + (((ch + 1) ^ (srow & 7)) << 3)] = k1;
#pragma unroll
      for (int i = 0; i < 8; ++i) {
        int c = sc0 + i;
        VtH[c * 64 + ((((srow >> 3) ^ (c & 7)) << 3)) + (srow & 7)] = v0[i];
      }
#pragma unroll
      for (int i = 0; i < 8; ++i) {
        int c = sc0 + 8 + i;
        VtH[c * 64 + ((((srow >> 3) ^ (c & 7)) << 3)) + (srow & 7)] = v1[i];
      }
    }
    __syncthreads();   // staged K/V visible

    f32x4 s[4];
#pragma unroll
    for (int ni = 0; ni < 4; ++ni) s[ni] = (f32x4){0.f, 0.f, 0.f, 0.f};
#pragma unroll
    for (int ks = 0; ks < 2; ++ks) {
      int sw = (((ks << 2) + l4) ^ (l15 & 7)) << 3;
      s16x8 ahh = *(const s16x8*)&AhH[(w * 16 + l15) * 64 + sw];
#pragma unroll
      for (int ni = 0; ni < 4; ++ni) {
        s16x8 kh = *(const s16x8*)&KH[(ni * 16 + l15) * 64 + sw];
        s[ni] = __builtin_amdgcn_mfma_f32_16x16x32_bf16(ahh, kh, s[ni], 0, 0, 0);
      }
    }
    __syncthreads();   // all waves done reading K -> P may overwrite KH

    // P = exp (masked), RNE; transpose-write into KH (wave-local rows).
#pragma unroll
    for (int ni = 0; ni < 4; ++ni) {
#pragma unroll
      for (int reg = 0; reg < 4; ++reg) {
        int jj = l15 + 16 * ni;
        float pv = (j0 + jj < jend) ? expf(s[ni][reg] * SCALE) : 0.f;
        rs[reg] += pv;
        int a = w * 16 + l4 * 4 + reg;
        KH[a * 64 + ((((jj >> 3) ^ (a & 7)) << 3)) + (jj & 7)] = bf16rne(pv);
      }
    }

    // O += P @ V (P reads wave-local)
#pragma unroll
    for (int ks = 0; ks < 2; ++ks) {
      int sw = (((ks << 2) + l4) ^ (l15 & 7)) << 3;
      s16x8 ph = *(const s16x8*)&KH[(w * 16 + l15) * 64 + sw];
#pragma unroll
      for (int ni = 0; ni < 4; ++ni) {
        s16x8 vh = *(const s16x8*)&VtH[(ni * 16 + l15) * 64 + sw];
        acc[ni] = __builtin_amdgcn_mfma_f32_16x16x32_bf16(ph, vh, acc[ni], 0, 0, 0);
      }
    }
  }

#pragma unroll
  for (int reg = 0; reg < 4; ++reg) {
    rs[reg] += __shfl_xor(rs[reg], 1);
    rs[reg] += __shfl_xor(rs[reg], 2);
    rs[reg] += __shfl_xor(rs[reg], 4);
    rs[reg] += __shfl_xor(rs[reg], 8);
  }
  const int basev = ((bg * Hh + h) * NCH + chunk) * (Aa * 64);
#pragma unroll
  for (int reg = 0; reg < 4; ++reg) {
    int a = w * 16 + l4 * 4 + reg;
    if (a < Aa) {
#pragma unroll
      for (int ni = 0; ni < 4; ++ni)
        paccv[basev + a * 64 + l15 + 16 * ni] = acc[ni][reg];
      if (l15 == 0)
        paccs[((bg * Hh + h) * NCH + chunk) * Aa + a] = rs[reg];
    }
  }
}

// ---------------------------------------------------------------------------
// Merge chunk partials -> avb[bgh,a,c] (RNE bf16)
// ---------------------------------------------------------------------------
__global__ __launch_bounds__(256) void merge_agent(
    const float* __restrict__ paccv, const float* __restrict__ paccs,
    short* __restrict__ avb) {
  const int bh = blockIdx.x;
  const int t = threadIdx.x;
  for (int idx = t; idx < Aa * HD; idx += 256) {
    int a = idx >> 6;
    float vs = 0.f, ss = 0.f;
#pragma unroll
    for (int ch = 0; ch < NCH; ++ch) {
      vs += paccv[(size_t)((bh * NCH + ch)) * (Aa * 64) + idx];
      ss += paccs[(bh * NCH + ch) * Aa + a];
    }
    avb[(size_t)bh * (Aa * HD) + idx] = bf16rne(vs / ss);
  }
}

// ---------------------------------------------------------------------------
// FUSED q attention + dwc + pack, MULTI-TILE: each block owns TPQ=4 q-tiles
// for one (bg,h); ah/av staged ONCE. olds stored as bf16 (adds <=1 ulp to O
// before dwc — under the output floor) so it avoids the AhH/AvH region.
// LDS ~34KB. Epilogue: O(bf16)->LDS, re-gather, 16B stores to Opk.
// ---------------------------------------------------------------------------
__global__ __launch_bounds__(256) void q_attn_dwc(
    const short* __restrict__ qkvb, const short* __restrict__ atb,
    const short* __restrict__ avb, const float* __restrict__ dwcw,
    const float* __restrict__ dwcb, short* __restrict__ Opk) {
  const int h = blockIdx.y, bg = blockIdx.z;
  __shared__ __align__(16) short SMEM[17296];   // 34592B
  short* AhH = SMEM;              // ah [a][d]   (4096)
  short* AvH = SMEM + 4096;       // av^T [c][a] (4096)
  short* QH  = SMEM + 8192;       // q [row][d]; P alias (4096)
  short* oldsb = SMEM + 8192;     // O bf16, stride 68 (4352; aliases QH)
  short* vlds = SMEM + 12544;     // v tile, stride 72 (4752)
  const int t = threadIdx.x;
  const int w = t >> 6, lane = t & 63, l15 = lane & 15, l4 = lane >> 4;

  // ---- stage ah + av^T once ----
  for (int idx = t; idx < 512; idx += 256) {
    int a = idx >> 3, c8 = idx & 7;
    s16x8 hv = (s16x8)(short)0, av8 = hv;
    if (a < Aa) {
      hv = *(const s16x8*)&atb[(size_t)(bg * Aa + a) * Cc + h * HD + c8 * 8];
      av8 = *(const s16x8*)&avb[(size_t)(bg * Hh + h) * (Aa * HD) + a * HD + c8 * 8];
    }
    *(s16x8*)&AhH[a * 64 + ((c8 ^ (a & 7)) << 3)] = hv;
#pragma unroll
    for (int i = 0; i < 8; ++i) {
      int c = c8 * 8 + i;
      AvH[c * 64 + ((((a >> 3) ^ (c & 7)) << 3)) + (a & 7)] = av8[i];
    }
  }

  for (int it2 = 0; it2 < TPQ; ++it2) {
    const int i0 = (blockIdx.x * TPQ + it2) * 64;
    if (i0 >= Nn) break;
    __syncthreads();   // iter 0: ah/av staged; else: prev re-gather done

    // ---- stage q tile ----
    {
      int row = t >> 2, c0 = (t & 3) * 16;
      int ig = i0 + row;
      s16x8 q0 = (s16x8)(short)0, q1 = q0;
      if (ig < Nn) {
        const short* p = &qkvb[(size_t)(bg * Nn + ig) * LDQ + h * HD + c0];
        q0 = *(const s16x8*)p;
        q1 = *(const s16x8*)(p + 8);
      }
      int ch = c0 >> 3;
      *(s16x8*)&QH[row * 64 + (((ch + 0) ^ (row & 7)) << 3)] = q0;
      *(s16x8*)&QH[row * 64 + (((ch + 1) ^ (row & 7)) << 3)] = q1;
    }
    __syncthreads();

    // ---- S = q @ ah^T ----
    f32x4 s[4];
#pragma unroll
    for (int ni = 0; ni < 4; ++ni) s[ni] = (f32x4){0.f, 0.f, 0.f, 0.f};
#pragma unroll
    for (int ks = 0; ks < 2; ++ks) {
      int sw = (((ks << 2) + l4) ^ (l15 & 7)) << 3;
      s16x8 qh = *(const s16x8*)&QH[(w * 16 + l15) * 64 + sw];
#pragma unroll
      for (int ni = 0; ni < 4; ++ni) {
        s16x8 bh = *(const s16x8*)&AhH[(ni * 16 + l15) * 64 + sw];
        s[ni] = __builtin_amdgcn_mfma_f32_16x16x32_bf16(qh, bh, s[ni], 0, 0, 0);
      }
    }
    __syncthreads();  // all waves done reading Q -> P may overwrite

    // ---- softmax over agents + transpose-write P (RNE) into QH ----
    float rsum[4] = {0.f, 0.f, 0.f, 0.f};
#pragma unroll
    for (int ni = 0; ni < 4; ++ni) {
#pragma unroll
      for (int reg = 0; reg < 4; ++reg) {
        int a = l15 + 16 * ni;
        float pv = (a < Aa) ? expf(s[ni][reg] * SCALE) : 0.f;
        s[ni][reg] = pv;
        rsum[reg] += pv;
      }
    }
#pragma unroll
    for (int reg = 0; reg < 4; ++reg) {
      rsum[reg] += __shfl_xor(rsum[reg], 1);
      rsum[reg] += __shfl_xor(rsum[reg], 2);
      rsum[reg] += __shfl_xor(rsum[reg], 4);
      rsum[reg] += __shfl_xor(rsum[reg], 8);
      rsum[reg] = 1.0f / rsum[reg];
    }
#pragma unroll
    for (int ni = 0; ni < 4; ++ni) {
#pragma unroll
      for (int reg = 0; reg < 4; ++reg) {
        int row = w * 16 + l4 * 4 + reg;
        int a = l15 + 16 * ni;
        QH[row * 64 + ((((a >> 3) ^ (row & 7)) << 3)) + (a & 7)] =
            bf16rne(s[ni][reg] * rsum[reg]);
      }
    }
    __syncthreads();

    // ---- O = P @ agent_v ----
    f32x4 o[4];
#pragma unroll
    for (int ni = 0; ni < 4; ++ni) o[ni] = (f32x4){0.f, 0.f, 0.f, 0.f};
#pragma unroll
    for (int ks = 0; ks < 2; ++ks) {
      int sw = (((ks << 2) + l4) ^ (l15 & 7)) << 3;
      s16x8 ph = *(const s16x8*)&QH[(w * 16 + l15) * 64 + sw];
#pragma unroll
      for (int ni = 0; ni < 4; ++ni) {
        s16x8 vh = *(const s16x8*)&AvH[(ni * 16 + l15) * 64 + sw];
        o[ni] = __builtin_amdgcn_mfma_f32_16x16x32_bf16(ph, vh, o[ni], 0, 0, 0);
      }
    }
    __syncthreads();  // P reads done -> oldsb (QH alias) may overwrite

    // ---- write O (bf16, stride 68) + stage v tile ----
#pragma unroll
    for (int reg = 0; reg < 4; ++reg) {
      int row = w * 16 + l4 * 4 + reg;
#pragma unroll
      for (int ni = 0; ni < 4; ++ni)
        oldsb[row * 68 + l15 + 16 * ni] = bf16rne(o[ni][reg]);
    }
    constexpr int VLD = 72;
    for (int idx = t; idx < 66 * 16; idx += 256) {
      int row = idx >> 4, cs = (idx & 15) << 2;
      int gr = i0 - 1 + row;
      s16x4 v = (s16x4)(short)0;
      if (gr >= 0 && gr < 4096)
        v = *(const s16x4*)&qkvb[((size_t)bg * Nn + gr) * LDQ + 2 * Cc + h * HD + cs];
      *(s16x4*)&vlds[row * VLD + cs] = v;
    }
    __syncthreads();

    // ---- re-gather: (local row, 8-ch chunk) -> one 16B store ----
#pragma unroll
    for (int it = 0; it < 2; ++it) {
      int widx = t + it * 256;            // 0..511
      int ml = widx >> 3, kc = widx & 7;
      int ig = i0 + ml;
      if (ig >= Nn) continue;
      s16x8 ov = *(const s16x8*)&oldsb[ml * 68 + kc * 8];
      float vals[8];
#pragma unroll
      for (int cI = 0; cI < 8; ++cI) vals[cI] = bf2f(ov[cI]);
      if (ig < Nn - 1) {
        const int rl = ml + 1;
        const short* vr = &vlds[rl * VLD + kc * 8];
#pragma unroll
        for (int cI = 0; cI < 8; ++cI) {
          int cg = h * HD + kc * 8 + cI;
          float vm = bf2f(vr[cI - VLD]);
          float v0 = bf2f(vr[cI]);
          float vp = bf2f(vr[cI + VLD]);
          vals[cI] += dwcw[cg * 3] * vm + dwcw[cg * 3 + 1] * v0 +
                      dwcw[cg * 3 + 2] * vp + dwcb[cg];
        }
      }
      s16x8 hv;
#pragma unroll
      for (int cI = 0; cI < 8; ++cI) hv[cI] = bf16rne(vals[cI]);
      const int mrow = bg * Nn + ig;
      const int win = h * 64;
      const int jj = (kc ^ (mrow & 7)) * 8;
      *(s16x8*)&Opk[(size_t)mrow * KA + win + jj] = hv;
    }
  }
}

}  // namespace

extern "C" void kernel_launch(void* const* d_in, const int* in_sizes, int n_in,
                              void* d_out, int out_size, void* d_ws,
                              size_t ws_size, hipStream_t stream) {
  const float* x = (const float*)d_in[0];
  const float* Wqkv = (const float*)d_in[1];
  const float* Wproj = (const float*)d_in[2];
  const float* bproj = (const float*)d_in[3];
  const float* dwcw = (const float*)d_in[4];
  const float* dwcb = (const float*)d_in[5];
  float* out = (float*)d_out;

  // --- fixed workspace: packed weight planes ---
  char* p = (char*)d_ws;
  short* WQpk = (short*)p; p += (size_t)LDQ * KP * 2;   // 7,077,888 B
  short* WPpk = (short*)p; p += (size_t)Cc * KP * 2;    // 2,359,296 B
  const size_t fixedBytes = (size_t)p - (size_t)d_ws;

  auto bytesFor = [&](int G) -> size_t {
    size_t Mg = (size_t)G * Nn;
    size_t Mpad = ((Mg + 127) / 128) * 128;
    size_t fl = (size_t)G * (Hh * NCH * Aa * 64 + Hh * NCH * Aa);  // paccv/s
    size_t sh = Mg * LDQ + (size_t)G * (Aa * Cc + Hh * Aa * HD) + Mpad * KA;
    return fixedBytes + fl * 4 + sh * 2;
  };
  int G = 1;
  for (int g = Bb; g >= 1; --g) {
    if (bytesFor(g) <= ws_size) { G = g; break; }
  }

  const size_t MgMax = (size_t)G * Nn;
  float* paccv = (float*)p;
  float* paccs = paccv + (size_t)G * Hh * NCH * Aa * 64;
  short* qkvb = (short*)(paccs + (size_t)G * Hh * NCH * Aa);
  short* atb = qkvb + MgMax * LDQ;
  short* avb = atb + (size_t)G * Aa * Cc;
  short* Apk = avb + (size_t)G * Hh * Aa * HD;   // aliased as Opk

  dim3 blk(256);
  // 0) pack weights (once per launch; deterministic)
  pack_w<<<dim3((96 * LDQ + 255) / 256), blk, 0, stream>>>(Wqkv, WQpk, LDQ);
  pack_w<<<dim3((96 * Cc + 255) / 256), blk, 0, stream>>>(Wproj, WPpk, Cc);

  for (int b0 = 0; b0 < Bb; b0 += G) {
    const int Gi = (b0 + G <= Bb) ? G : (Bb - b0);
    const int Mg = Gi * Nn;
    const int Mtiles = (Mg + 127) / 128;
    const float* xg = x + (size_t)b0 * Nn * Cc;
    float* outg = out + (size_t)b0 * Nn * Cc;

    // 1) pack x (RNE) -> Apk, then qkv (bf16) = x @ Wqkv
    pack_act<<<dim3((Mg * 96 + 255) / 256), blk, 0, stream>>>(xg, Apk, Mg);
    {
      const int nch = LDQ / 128;            // 18
      const int nwg = Mtiles * nch;
      gemm_pk2<true><<<dim3(nwg), blk, 0, stream>>>(Apk, WQpk, qkvb, nullptr,
                                                    Mg, LDQ, nch, nwg);
    }
    // 2) agent tokens (adaptive pool of bf16 q) -> atb (bf16)
    pool_agents<<<dim3(Gi * Aa), dim3(192), 0, stream>>>(qkvb, atb);
    // 3) agent attention partials (MFMA) + merge -> avb (bf16)
    agent_attn_mfma<<<dim3(NCH, Hh, Gi), blk, 0, stream>>>(qkvb, atb, paccv,
                                                           paccs);
    merge_agent<<<dim3(Gi * Hh), blk, 0, stream>>>(paccv, paccs, avb);
    // 4) fused q attention + dwc + pack (multi-tile) -> Opk(=Apk)
    {
      const int qtiles = (Nn + 63) / 64;                // 65
      q_attn_dwc<<<dim3((qtiles + TPQ - 1) / TPQ, Hh, Gi), blk, 0, stream>>>(
          qkvb, atb, avb, dwcw, dwcb, Apk);
    }
    // 5) final projection (fp32 out, +bias)
    {
      const int nch = Cc / 128;             // 6
      const int nwg = Mtiles * nch;
      gemm_pk2<false><<<dim3(nwg), blk, 0, stream>>>(Apk, WPpk, outg, bproj,
                                                     Mg, Cc, nch, nwg);
    }
  }
}

// Round 21
// 525.749 us; speedup vs baseline: 1.0150x; 1.0150x over previous
//
#include <hip/hip_runtime.h>

namespace {

constexpr int Bb = 8;
constexpr int Nn = 4097;
constexpr int Cc = 768;
constexpr int Hh = 12;
constexpr int HD = 64;
constexpr int Aa = 49;
constexpr int LDQ = 3 * Cc;        // 2304 (qkv row stride, in shorts)
constexpr int NCH = 16;            // j-chunks for agent attention
constexpr int CHUNK = 256;         // 64-aligned; last chunk absorbs row 4096
constexpr float SCALE = 0.125f;    // hd^-0.5
constexpr int KP = 1536;           // WEIGHT packed row length (hi 768|lo 768)
constexpr int KA = 768;            // ACTIVATION packed row length (RNE bf16)

typedef short s16x8 __attribute__((ext_vector_type(8)));
typedef short s16x4 __attribute__((ext_vector_type(4)));
typedef float f32x4 __attribute__((ext_vector_type(4)));

struct HL { short h, l; };

// Split fp32 into hi (truncated bf16, exact bits) + lo (RNE bf16 of residual).
__device__ inline HL splitbf(float v) {
  unsigned u = __float_as_uint(v);
  HL r;
  r.h = (short)(u >> 16);
  float hf = __uint_as_float(u & 0xffff0000u);
  float lf = v - hf;
  unsigned ul = __float_as_uint(lf);
  r.l = (short)((ul + 0x7fffu + ((ul >> 16) & 1u)) >> 16);
  return r;
}

__device__ inline short bf16rne(float v) {
  unsigned u = __float_as_uint(v);
  return (short)((u + 0x7fffu + ((u >> 16) & 1u)) >> 16);
}
__device__ inline float bf2f(short s) {
  return __uint_as_float((unsigned)(unsigned short)s << 16);
}

// async global->LDS, 16B per lane (linear dest)
__device__ inline void gload16(const short* g, void* l) {
  __builtin_amdgcn_global_load_lds(
      (const __attribute__((address_space(1))) void*)g,
      (__attribute__((address_space(3))) void*)l, 16, 0, 0);
}

// Packed layout: per row, 12 windows of 64 elems (8 chunks of 8);
// physical chunk = logical chunk ^ (row&7).
// Weights: split hi/lo (REQUIRED — RNE-only W fails threshold through K=768).
// Activations/attention operands: single RNE bf16 (softmax-attenuated error).
// qkv / at / av stored as RNE bf16 (every consumer RNE'd them anyway).

// ---------------------------------------------------------------------------
// Pack activations: src[M][768] fp32 -> dst[M][768] RNE bf16 (swizzled).
// ---------------------------------------------------------------------------
__global__ __launch_bounds__(256) void pack_act(
    const float* __restrict__ src, short* __restrict__ dst, int M) {
  int idx = blockIdx.x * 256 + threadIdx.x;
  if (idx >= M * 96) return;
  int m = idx / 96, kc = idx - m * 96;
  const float* s = src + (size_t)m * 768 + kc * 8;
  float4 v0 = *(const float4*)s;
  float4 v1 = *(const float4*)(s + 4);
  s16x8 hv;
  hv[0] = bf16rne(v0.x); hv[1] = bf16rne(v0.y);
  hv[2] = bf16rne(v0.z); hv[3] = bf16rne(v0.w);
  hv[4] = bf16rne(v1.x); hv[5] = bf16rne(v1.y);
  hv[6] = bf16rne(v1.z); hv[7] = bf16rne(v1.w);
  int win = (kc >> 3) * 64;
  int jj = ((kc & 7) ^ (m & 7)) * 8;
  *(s16x8*)&dst[(size_t)m * KA + win + jj] = hv;
}

// ---------------------------------------------------------------------------
// Pack weights: W[768][N] fp32 -> Wpk[N][1536] bf16 split, key (n&7).
// ---------------------------------------------------------------------------
__global__ __launch_bounds__(256) void pack_w(
    const float* __restrict__ W, short* __restrict__ Wpk, int N) {
  int idx = blockIdx.x * 256 + threadIdx.x;
  if (idx >= 96 * N) return;
  int kc = idx / N, n = idx - kc * N;
  s16x8 hv, lv;
#pragma unroll
  for (int i = 0; i < 8; ++i) {
    HL r = splitbf(W[(size_t)(kc * 8 + i) * N + n]);
    hv[i] = r.h; lv[i] = r.l;
  }
  int win = (kc >> 3) * 64;
  int jj = ((kc & 7) ^ (n & 7)) * 8;
  short* d = Wpk + (size_t)n * KP;
  *(s16x8*)&d[win + jj] = hv;
  *(s16x8*)&d[768 + win + jj] = lv;
}

// ---------------------------------------------------------------------------
// C[M x N] = A @ B (+bias): A = RNE bf16 [M][768], B = split [N][1536].
// 2 products -> 64 MFMA per kt, 3 staged planes (48KB LDS). R12 barrier
// structure (frozen). BF16OUT: direct RNE bf16 stores.
// ---------------------------------------------------------------------------
template <bool BF16OUT>
__global__ __launch_bounds__(256) void gemm_pk2(
    const short* __restrict__ Apk, const short* __restrict__ Bpk,
    void* __restrict__ Cm, const float* __restrict__ bias,
    int Mr, int ldc, int nch, int nwg) {
  __shared__ __align__(16) short AsH[128 * 64];
  __shared__ __align__(16) short BsH[128 * 64], BsL[128 * 64];
  const int t = threadIdx.x;
  const int lane = t & 63;
  const int w = t >> 6;
  const int wr = w >> 1, wc = w & 1;
  const int l15 = lane & 15, l4 = lane >> 4;

  const int j = blockIdx.x;
  const int q = nwg >> 3, r = nwg & 7;
  const int xcd = j & 7, pos = j >> 3;
  const int logical =
      (xcd < r ? xcd * (q + 1) : r * (q + 1) + (xcd - r) * q) + pos;
  const int mt = logical / nch, nc = logical - mt * nch;
  const int m0 = mt * 128, n0 = nc * 128;

  f32x4 acc[4][4];
#pragma unroll
  for (int mi = 0; mi < 4; ++mi)
#pragma unroll
    for (int ni = 0; ni < 4; ++ni) acc[mi][ni] = (f32x4){0.f, 0.f, 0.f, 0.f};

  for (int kt = 0; kt < 12; ++kt) {
    const short* Ab = Apk + (size_t)m0 * KA + kt * 64;
    const short* Bt = Bpk + (size_t)n0 * KP + kt * 64;
    __syncthreads();
#pragma unroll
    for (int i = 0; i < 4; ++i) {
      const int o = (i * 256 + t) * 16;   // byte offset in 16KB plane
      const int row = o >> 7;
      const int ce = (o & 127) >> 1;      // element col (physical)
      gload16(Ab + (size_t)row * KA + ce, (char*)AsH + o);
      gload16(Bt + (size_t)row * KP + ce, (char*)BsH + o);
      gload16(Bt + (size_t)row * KP + 768 + ce, (char*)BsL + o);
    }
    __syncthreads();
#pragma unroll
    for (int ks = 0; ks < 2; ++ks) {
      s16x8 ah[4], bh[4], bl[4];
#pragma unroll
      for (int mi = 0; mi < 4; ++mi) {
        int rr = wr * 64 + mi * 16 + l15;
        ah[mi] = *(const s16x8*)&AsH[rr * 64 + ((((ks << 2) + l4) ^ (l15 & 7)) << 3)];
      }
#pragma unroll
      for (int ni = 0; ni < 4; ++ni) {
        int rr = wc * 64 + ni * 16 + l15;
        int off = rr * 64 + ((((ks << 2) + l4) ^ (l15 & 7)) << 3);
        bh[ni] = *(const s16x8*)&BsH[off];
        bl[ni] = *(const s16x8*)&BsL[off];
      }
#pragma unroll
      for (int mi = 0; mi < 4; ++mi)
#pragma unroll
        for (int ni = 0; ni < 4; ++ni) {
          acc[mi][ni] = __builtin_amdgcn_mfma_f32_16x16x32_bf16(
              ah[mi], bh[ni], acc[mi][ni], 0, 0, 0);
          acc[mi][ni] = __builtin_amdgcn_mfma_f32_16x16x32_bf16(
              ah[mi], bl[ni], acc[mi][ni], 0, 0, 0);
        }
    }
  }

#pragma unroll
  for (int mi = 0; mi < 4; ++mi) {
#pragma unroll
    for (int jr = 0; jr < 4; ++jr) {
      int gr = m0 + wr * 64 + mi * 16 + l4 * 4 + jr;
      if (gr < Mr) {
#pragma unroll
        for (int ni = 0; ni < 4; ++ni) {
          int gc = n0 + wc * 64 + ni * 16 + l15;
          float v = acc[mi][ni][jr];
          if (bias) v += bias[gc];
          if constexpr (BF16OUT) {
            ((short*)Cm)[(size_t)gr * ldc + gc] = bf16rne(v);
          } else {
            ((float*)Cm)[(size_t)gr * ldc + gc] = v;
          }
        }
      }
    }
  }
}

// ---------------------------------------------------------------------------
// Adaptive-pool agents: atb[bg,a,c] = RNE(mean over q rows of bf16 q).
// ---------------------------------------------------------------------------
__global__ __launch_bounds__(192) void pool_agents(
    const short* __restrict__ qkvb, short* __restrict__ atb) {
  const int ba = blockIdx.x;
  const int bg = ba / Aa, a = ba % Aa;
  const int s = (a * 4096) / 49;
  const int e = ((a + 1) * 4096 + 48) / 49;
  const float w = 1.0f / (float)(e - s);
  const int c4 = threadIdx.x * 4;
  f32x4 sum = (f32x4){0.f, 0.f, 0.f, 0.f};
  for (int l = s; l < e; ++l) {
    const s16x4 v = *(const s16x4*)&qkvb[(size_t)(bg * Nn + l) * LDQ + c4];
    sum[0] += bf2f(v[0]); sum[1] += bf2f(v[1]);
    sum[2] += bf2f(v[2]); sum[3] += bf2f(v[3]);
  }
  s16x4 o;
  o[0] = bf16rne(sum[0] * w); o[1] = bf16rne(sum[1] * w);
  o[2] = bf16rne(sum[2] * w); o[3] = bf16rne(sum[3] * w);
  *(s16x4*)&atb[(size_t)(bg * Aa + a) * Cc + c4] = o;
}

// ---------------------------------------------------------------------------
// Agent attention: all operands RNE bf16, staging = direct bit-copy.
// 24KB LDS -> 6 blocks/CU. 3 barriers/tile.
// ---------------------------------------------------------------------------
__global__ __launch_bounds__(256) void agent_attn_mfma(
    const short* __restrict__ qkvb, const short* __restrict__ atb,
    float* __restrict__ paccv, float* __restrict__ paccs) {
  const int chunk = blockIdx.x, h = blockIdx.y, bg = blockIdx.z;
  __shared__ __align__(16) short AhH[4096];   // ah [a][d]
  __shared__ __align__(16) short KH[4096];    // K [j][d]; P aliases
  __shared__ __align__(16) short VtH[4096];   // V^T [c][j]
  const int t = threadIdx.x;
  const int w = t >> 6, lane = t & 63, l15 = lane & 15, l4 = lane >> 4;

  for (int idx = t; idx < 512; idx += 256) {
    int a = idx >> 3, c8 = idx & 7;
    s16x8 hv = (s16x8)(short)0;
    if (a < Aa)
      hv = *(const s16x8*)&atb[(size_t)(bg * Aa + a) * Cc + h * HD + c8 * 8];
    *(s16x8*)&AhH[a * 64 + ((c8 ^ (a & 7)) << 3)] = hv;
  }

  f32x4 acc[4];
#pragma unroll
  for (int ni = 0; ni < 4; ++ni) acc[ni] = (f32x4){0.f, 0.f, 0.f, 0.f};
  float rs[4] = {0.f, 0.f, 0.f, 0.f};

  const int jstart = chunk * CHUNK;
  const int jend = (chunk == NCH - 1) ? Nn : jstart + CHUNK;
  const int srow = t >> 2, sc0 = (t & 3) * 16;

  for (int j0 = jstart; j0 < jend; j0 += 64) {
    __syncthreads();   // prev tile's S/PV reads done
    {
      int jg = j0 + srow;
      s16x8 k0 = (s16x8)(short)0, k1 = k0, v0 = k0, v1 = k0;
      if (jg < jend) {
        const short* p = &qkvb[(size_t)(bg * Nn + jg) * LDQ + Cc + h * HD + sc0];
        k0 = *(const s16x8*)p;
        k1 = *(const s16x8*)(p + 8);
        v0 = *(const s16x8*)(p + Cc);
        v1 = *(const s16x8*)(p + Cc + 8);
      }
      int ch = sc0 >> 3;
      *(s16x8*)&KH[srow * 64 + (((ch + 0) ^ (srow & 7)) << 3)] = k0;
      *(s16x8*)&KH[srow * 64 + (((ch + 1) ^ (srow & 7)) << 3)] = k1;
#pragma unroll
      for (int i = 0; i < 8; ++i) {
        int c = sc0 + i;
        VtH[c * 64 + ((((srow >> 3) ^ (c & 7)) << 3)) + (srow & 7)] = v0[i];
      }
#pragma unroll
      for (int i = 0; i < 8; ++i) {
        int c = sc0 + 8 + i;
        VtH[c * 64 + ((((srow >> 3) ^ (c & 7)) << 3)) + (srow & 7)] = v1[i];
      }
    }
    __syncthreads();   // staged K/V visible

    f32x4 s[4];
#pragma unroll
    for (int ni = 0; ni < 4; ++ni) s[ni] = (f32x4){0.f, 0.f, 0.f, 0.f};
#pragma unroll
    for (int ks = 0; ks < 2; ++ks) {
      int sw = (((ks << 2) + l4) ^ (l15 & 7)) << 3;
      s16x8 ahh = *(const s16x8*)&AhH[(w * 16 + l15) * 64 + sw];
#pragma unroll
      for (int ni = 0; ni < 4; ++ni) {
        s16x8 kh = *(const s16x8*)&KH[(ni * 16 + l15) * 64 + sw];
        s[ni] = __builtin_amdgcn_mfma_f32_16x16x32_bf16(ahh, kh, s[ni], 0, 0, 0);
      }
    }
    __syncthreads();   // all waves done reading K -> P may overwrite KH

    // P = exp (masked), RNE; transpose-write into KH (wave-local rows).
#pragma unroll
    for (int ni = 0; ni < 4; ++ni) {
#pragma unroll
      for (int reg = 0; reg < 4; ++reg) {
        int jj = l15 + 16 * ni;
        float pv = (j0 + jj < jend) ? expf(s[ni][reg] * SCALE) : 0.f;
        rs[reg] += pv;
        int a = w * 16 + l4 * 4 + reg;
        KH[a * 64 + ((((jj >> 3) ^ (a & 7)) << 3)) + (jj & 7)] = bf16rne(pv);
      }
    }

    // O += P @ V (P reads wave-local)
#pragma unroll
    for (int ks = 0; ks < 2; ++ks) {
      int sw = (((ks << 2) + l4) ^ (l15 & 7)) << 3;
      s16x8 ph = *(const s16x8*)&KH[(w * 16 + l15) * 64 + sw];
#pragma unroll
      for (int ni = 0; ni < 4; ++ni) {
        s16x8 vh = *(const s16x8*)&VtH[(ni * 16 + l15) * 64 + sw];
        acc[ni] = __builtin_amdgcn_mfma_f32_16x16x32_bf16(ph, vh, acc[ni], 0, 0, 0);
      }
    }
  }

#pragma unroll
  for (int reg = 0; reg < 4; ++reg) {
    rs[reg] += __shfl_xor(rs[reg], 1);
    rs[reg] += __shfl_xor(rs[reg], 2);
    rs[reg] += __shfl_xor(rs[reg], 4);
    rs[reg] += __shfl_xor(rs[reg], 8);
  }
  const int basev = ((bg * Hh + h) * NCH + chunk) * (Aa * 64);
#pragma unroll
  for (int reg = 0; reg < 4; ++reg) {
    int a = w * 16 + l4 * 4 + reg;
    if (a < Aa) {
#pragma unroll
      for (int ni = 0; ni < 4; ++ni)
        paccv[basev + a * 64 + l15 + 16 * ni] = acc[ni][reg];
      if (l15 == 0)
        paccs[((bg * Hh + h) * NCH + chunk) * Aa + a] = rs[reg];
    }
  }
}

// ---------------------------------------------------------------------------
// Merge chunk partials -> avb[bgh,a,c] (RNE bf16)
// ---------------------------------------------------------------------------
__global__ __launch_bounds__(256) void merge_agent(
    const float* __restrict__ paccv, const float* __restrict__ paccs,
    short* __restrict__ avb) {
  const int bh = blockIdx.x;
  const int t = threadIdx.x;
  for (int idx = t; idx < Aa * HD; idx += 256) {
    int a = idx >> 6;
    float vs = 0.f, ss = 0.f;
#pragma unroll
    for (int ch = 0; ch < NCH; ++ch) {
      vs += paccv[(size_t)((bh * NCH + ch)) * (Aa * 64) + idx];
      ss += paccs[(bh * NCH + ch) * Aa + a];
    }
    avb[(size_t)bh * (Aa * HD) + idx] = bf16rne(vs / ss);
  }
}

// ---------------------------------------------------------------------------
// FUSED q attention + dwc + pack (R18 single-tile form — best measured;
// the TPQ=4 multi-tile variant regressed ~10us in R20). All operands RNE
// bf16; staging = bit-copies. ~27KB LDS.
// ---------------------------------------------------------------------------
__global__ __launch_bounds__(256) void q_attn_dwc(
    const short* __restrict__ qkvb, const short* __restrict__ atb,
    const short* __restrict__ avb, const float* __restrict__ dwcw,
    const float* __restrict__ dwcb, short* __restrict__ Opk) {
  const int i0 = blockIdx.x * 64, h = blockIdx.y, bg = blockIdx.z;
  __shared__ __align__(16) short SMEM[13568];   // 27136B
  short* AhH = SMEM;             // ah [a][d]   (8KB)
  short* AvH = SMEM + 4096;      // av^T [c][a] (8KB)
  short* QH  = SMEM + 8192;      // q [row][d]; P alias (8KB)
  const int t = threadIdx.x;
  const int w = t >> 6, lane = t & 63, l15 = lane & 15, l4 = lane >> 4;

  for (int idx = t; idx < 512; idx += 256) {
    int a = idx >> 3, c8 = idx & 7;
    s16x8 hv = (s16x8)(short)0, av8 = hv;
    if (a < Aa) {
      hv = *(const s16x8*)&atb[(size_t)(bg * Aa + a) * Cc + h * HD + c8 * 8];
      av8 = *(const s16x8*)&avb[(size_t)(bg * Hh + h) * (Aa * HD) + a * HD + c8 * 8];
    }
    *(s16x8*)&AhH[a * 64 + ((c8 ^ (a & 7)) << 3)] = hv;
#pragma unroll
    for (int i = 0; i < 8; ++i) {
      int c = c8 * 8 + i;
      AvH[c * 64 + ((((a >> 3) ^ (c & 7)) << 3)) + (a & 7)] = av8[i];
    }
  }
  {
    int row = t >> 2, c0 = (t & 3) * 16;
    int ig = i0 + row;
    s16x8 q0 = (s16x8)(short)0, q1 = q0;
    if (ig < Nn) {
      const short* p = &qkvb[(size_t)(bg * Nn + ig) * LDQ + h * HD + c0];
      q0 = *(const s16x8*)p;
      q1 = *(const s16x8*)(p + 8);
    }
    int ch = c0 >> 3;
    *(s16x8*)&QH[row * 64 + (((ch + 0) ^ (row & 7)) << 3)] = q0;
    *(s16x8*)&QH[row * 64 + (((ch + 1) ^ (row & 7)) << 3)] = q1;
  }
  __syncthreads();

  // ---- S = q @ ah^T (1 product) ----
  f32x4 s[4];
#pragma unroll
  for (int ni = 0; ni < 4; ++ni) s[ni] = (f32x4){0.f, 0.f, 0.f, 0.f};
#pragma unroll
  for (int ks = 0; ks < 2; ++ks) {
    int sw = (((ks << 2) + l4) ^ (l15 & 7)) << 3;
    s16x8 qh = *(const s16x8*)&QH[(w * 16 + l15) * 64 + sw];
#pragma unroll
    for (int ni = 0; ni < 4; ++ni) {
      s16x8 bh = *(const s16x8*)&AhH[(ni * 16 + l15) * 64 + sw];
      s[ni] = __builtin_amdgcn_mfma_f32_16x16x32_bf16(qh, bh, s[ni], 0, 0, 0);
    }
  }
  __syncthreads();  // all waves done reading Q -> P may overwrite

  // ---- softmax over agents + transpose-write P (RNE) into QH ----
  float rsum[4] = {0.f, 0.f, 0.f, 0.f};
#pragma unroll
  for (int ni = 0; ni < 4; ++ni) {
#pragma unroll
    for (int reg = 0; reg < 4; ++reg) {
      int a = l15 + 16 * ni;
      float pv = (a < Aa) ? expf(s[ni][reg] * SCALE) : 0.f;
      s[ni][reg] = pv;
      rsum[reg] += pv;
    }
  }
#pragma unroll
  for (int reg = 0; reg < 4; ++reg) {
    rsum[reg] += __shfl_xor(rsum[reg], 1);
    rsum[reg] += __shfl_xor(rsum[reg], 2);
    rsum[reg] += __shfl_xor(rsum[reg], 4);
    rsum[reg] += __shfl_xor(rsum[reg], 8);
    rsum[reg] = 1.0f / rsum[reg];
  }
#pragma unroll
  for (int ni = 0; ni < 4; ++ni) {
#pragma unroll
    for (int reg = 0; reg < 4; ++reg) {
      int row = w * 16 + l4 * 4 + reg;
      int a = l15 + 16 * ni;
      QH[row * 64 + ((((a >> 3) ^ (row & 7)) << 3)) + (a & 7)] =
          bf16rne(s[ni][reg] * rsum[reg]);
    }
  }
  __syncthreads();

  // ---- O = P @ agent_v (1 product) ----
  f32x4 o[4];
#pragma unroll
  for (int ni = 0; ni < 4; ++ni) o[ni] = (f32x4){0.f, 0.f, 0.f, 0.f};
#pragma unroll
  for (int ks = 0; ks < 2; ++ks) {
    int sw = (((ks << 2) + l4) ^ (l15 & 7)) << 3;
    s16x8 ph = *(const s16x8*)&QH[(w * 16 + l15) * 64 + sw];
#pragma unroll
    for (int ni = 0; ni < 4; ++ni) {
      s16x8 vh = *(const s16x8*)&AvH[(ni * 16 + l15) * 64 + sw];
      o[ni] = __builtin_amdgcn_mfma_f32_16x16x32_bf16(ph, vh, o[ni], 0, 0, 0);
    }
  }
  __syncthreads();  // all LDS dead -> olds / vlds may overwrite

  // ---- write O to LDS (stride 68) + stage v tile (bit-copy) ----
  float* olds = (float*)SMEM;                              // 17408B
  short* vlds = SMEM + 8704;                               // 9504B, disjoint
#pragma unroll
  for (int reg = 0; reg < 4; ++reg) {
    int row = w * 16 + l4 * 4 + reg;
#pragma unroll
    for (int ni = 0; ni < 4; ++ni)
      olds[row * 68 + l15 + 16 * ni] = o[ni][reg];
  }
  constexpr int VLD = 72;
  for (int idx = t; idx < 66 * 16; idx += 256) {
    int row = idx >> 4, cs = (idx & 15) << 2;
    int gr = i0 - 1 + row;
    s16x4 v = (s16x4)(short)0;
    if (gr >= 0 && gr < 4096)
      v = *(const s16x4*)&qkvb[((size_t)bg * Nn + gr) * LDQ + 2 * Cc + h * HD + cs];
    *(s16x4*)&vlds[row * VLD + cs] = v;
  }
  __syncthreads();

  // ---- re-gather: (local row, 8-ch chunk) -> one 16B store ----
#pragma unroll
  for (int it = 0; it < 2; ++it) {
    int widx = t + it * 256;            // 0..511
    int ml = widx >> 3, kc = widx & 7;
    int ig = i0 + ml;
    if (ig >= Nn) continue;
    float vals[8];
    *(float4*)&vals[0] = *(const float4*)&olds[ml * 68 + kc * 8];
    *(float4*)&vals[4] = *(const float4*)&olds[ml * 68 + kc * 8 + 4];
    if (ig < Nn - 1) {
      const int rl = ml + 1;
      const short* vr = &vlds[rl * VLD + kc * 8];
#pragma unroll
      for (int cI = 0; cI < 8; ++cI) {
        int cg = h * HD + kc * 8 + cI;
        float vm = bf2f(vr[cI - VLD]);
        float v0 = bf2f(vr[cI]);
        float vp = bf2f(vr[cI + VLD]);
        vals[cI] += dwcw[cg * 3] * vm + dwcw[cg * 3 + 1] * v0 +
                    dwcw[cg * 3 + 2] * vp + dwcb[cg];
      }
    }
    s16x8 hv;
#pragma unroll
    for (int cI = 0; cI < 8; ++cI) hv[cI] = bf16rne(vals[cI]);
    const int mrow = bg * Nn + ig;
    const int win = h * 64;
    const int jj = (kc ^ (mrow & 7)) * 8;
    *(s16x8*)&Opk[(size_t)mrow * KA + win + jj] = hv;
  }
}

}  // namespace

extern "C" void kernel_launch(void* const* d_in, const int* in_sizes, int n_in,
                              void* d_out, int out_size, void* d_ws,
                              size_t ws_size, hipStream_t stream) {
  const float* x = (const float*)d_in[0];
  const float* Wqkv = (const float*)d_in[1];
  const float* Wproj = (const float*)d_in[2];
  const float* bproj = (const float*)d_in[3];
  const float* dwcw = (const float*)d_in[4];
  const float* dwcb = (const float*)d_in[5];
  float* out = (float*)d_out;

  // --- fixed workspace: packed weight planes ---
  char* p = (char*)d_ws;
  short* WQpk = (short*)p; p += (size_t)LDQ * KP * 2;   // 7,077,888 B
  short* WPpk = (short*)p; p += (size_t)Cc * KP * 2;    // 2,359,296 B
  const size_t fixedBytes = (size_t)p - (size_t)d_ws;

  auto bytesFor = [&](int G) -> size_t {
    size_t Mg = (size_t)G * Nn;
    size_t Mpad = ((Mg + 127) / 128) * 128;
    size_t fl = (size_t)G * (Hh * NCH * Aa * 64 + Hh * NCH * Aa);  // paccv/s
    size_t sh = Mg * LDQ + (size_t)G * (Aa * Cc + Hh * Aa * HD) + Mpad * KA;
    return fixedBytes + fl * 4 + sh * 2;
  };
  int G = 1;
  for (int g = Bb; g >= 1; --g) {
    if (bytesFor(g) <= ws_size) { G = g; break; }
  }

  const size_t MgMax = (size_t)G * Nn;
  float* paccv = (float*)p;
  float* paccs = paccv + (size_t)G * Hh * NCH * Aa * 64;
  short* qkvb = (short*)(paccs + (size_t)G * Hh * NCH * Aa);
  short* atb = qkvb + MgMax * LDQ;
  short* avb = atb + (size_t)G * Aa * Cc;
  short* Apk = avb + (size_t)G * Hh * Aa * HD;   // aliased as Opk

  dim3 blk(256);
  // 0) pack weights (once per launch; deterministic)
  pack_w<<<dim3((96 * LDQ + 255) / 256), blk, 0, stream>>>(Wqkv, WQpk, LDQ);
  pack_w<<<dim3((96 * Cc + 255) / 256), blk, 0, stream>>>(Wproj, WPpk, Cc);

  for (int b0 = 0; b0 < Bb; b0 += G) {
    const int Gi = (b0 + G <= Bb) ? G : (Bb - b0);
    const int Mg = Gi * Nn;
    const int Mtiles = (Mg + 127) / 128;
    const float* xg = x + (size_t)b0 * Nn * Cc;
    float* outg = out + (size_t)b0 * Nn * Cc;

    // 1) pack x (RNE) -> Apk, then qkv (bf16) = x @ Wqkv
    pack_act<<<dim3((Mg * 96 + 255) / 256), blk, 0, stream>>>(xg, Apk, Mg);
    {
      const int nch = LDQ / 128;            // 18
      const int nwg = Mtiles * nch;
      gemm_pk2<true><<<dim3(nwg), blk, 0, stream>>>(Apk, WQpk, qkvb, nullptr,
                                                    Mg, LDQ, nch, nwg);
    }
    // 2) agent tokens (adaptive pool of bf16 q) -> atb (bf16)
    pool_agents<<<dim3(Gi * Aa), dim3(192), 0, stream>>>(qkvb, atb);
    // 3) agent attention partials (MFMA) + merge -> avb (bf16)
    agent_attn_mfma<<<dim3(NCH, Hh, Gi), blk, 0, stream>>>(qkvb, atb, paccv,
                                                           paccs);
    merge_agent<<<dim3(Gi * Hh), blk, 0, stream>>>(paccv, paccs, avb);
    // 4) fused q attention + dwc + pack (RNE) -> Opk(=Apk)
    q_attn_dwc<<<dim3((Nn + 63) / 64, Hh, Gi), blk, 0, stream>>>(
        qkvb, atb, avb, dwcw, dwcb, Apk);
    // 5) final projection (fp32 out, +bias)
    {
      const int nch = Cc / 128;             // 6
      const int nwg = Mtiles * nch;
      gemm_pk2<false><<<dim3(nwg), blk, 0, stream>>>(Apk, WPpk, outg, bproj,
                                                     Mg, Cc, nch, nwg);
    }
  }
}